// Round 1
// baseline (144.699 us; speedup 1.0000x reference)
//
#include <hip/hip_runtime.h>
#include <hip/hip_bf16.h>

#define G_ 8
#define GIN_ 256
#define GOUT_ 256
#define NROWS_ 8192
#define LDX_ 2048   // = G_*GIN_ = row stride of x and out

typedef __attribute__((ext_vector_type(4))) float f32x4;
typedef __attribute__((ext_vector_type(8))) short bf16x8;

// ---------------------------------------------------------------------------
// Prep: W [G][GIN][GOUT] f32  ->  Wt [G][GOUT][GIN] bf16 (transposed+converted)
// so the main kernel can stage B fragments with global_load_lds width=16.
// Grid: G * (GOUT/64) * (GIN/64) = 128 blocks x 256 threads. LDS-tiled
// transpose: both the global read and the global write are coalesced.
// ---------------------------------------------------------------------------
__global__ __launch_bounds__(256) void wprep_kernel(const float* __restrict__ W,
                                                    __hip_bfloat16* __restrict__ Wt) {
    __shared__ float tile[64][65];   // +1 pad: conflict-free transposed read
    const int bid = blockIdx.x;
    const int g  = bid >> 4;
    const int ot = (bid >> 2) & 3;   // o-tile (64 wide)
    const int it = bid & 3;          // i-tile (64 wide)
    const float* Wg = W + g * GIN_ * GOUT_;
    __hip_bfloat16* Wtg = Wt + g * GIN_ * GOUT_;
    const int lane_o = threadIdx.x & 63;
    const int sub    = threadIdx.x >> 6;   // 0..3
#pragma unroll
    for (int r = 0; r < 16; ++r) {
        int i = r * 4 + sub;
        tile[i][lane_o] = Wg[(it * 64 + i) * GOUT_ + ot * 64 + lane_o];
    }
    __syncthreads();
#pragma unroll
    for (int r = 0; r < 16; ++r) {
        int o = r * 4 + sub;
        // Wt[o][i] = W[i][o]; i = lane_o contiguous -> coalesced 128B store
        Wtg[(ot * 64 + o) * GIN_ + it * 64 + lane_o] = __float2bfloat16(tile[lane_o][o]);
    }
}

// ---------------------------------------------------------------------------
// Main fused kernel: grouped GEMM (bf16 MFMA, fp32 acc) + bias + rational.
// Grid: (8192/128) * (G * 256/128) = 64 * 16 = 1024 blocks x 256 threads.
// Per block: 128(M) x 128(N) tile of one group's GEMM; BK=32, 8 K-iters.
// 4 waves, each computes a 64x64 subtile via 4x4 mfma_f32_16x16x32_bf16.
// ---------------------------------------------------------------------------
__global__ __launch_bounds__(256) void gkan_kernel(const float* __restrict__ x,
                                                   const __hip_bfloat16* __restrict__ Wt,
                                                   const float* __restrict__ bias,
                                                   const float* __restrict__ pc,
                                                   const float* __restrict__ qc,
                                                   float* __restrict__ out) {
    // As: [m][k] 128x32 bf16 (row = 64 B).  Bs: [n][k] 128x32 bf16.
    __shared__ __align__(16) __hip_bfloat16 As[128 * 32];
    __shared__ __align__(16) __hip_bfloat16 Bs[128 * 32];

    const int bid   = blockIdx.x;
    const int mtile = bid & 63;
    const int nid   = bid >> 6;    // 0..15
    const int g     = nid >> 1;
    const int ntile = nid & 1;

    const int m0 = mtile * 128;
    const int n0 = ntile * 128;    // within this group's 256 outputs

    const int t    = threadIdx.x;
    const int wave = t >> 6;
    const int lane = t & 63;
    const int lm   = lane & 15;
    const int quad = lane >> 4;
    const int wrow = wave >> 1;    // wave's 64-row block within 128
    const int wcol = wave & 1;     // wave's 64-col block within 128

    const float* xg = x + (size_t)m0 * LDX_ + g * GIN_;
    const __hip_bfloat16* Wtg = Wt + (size_t)g * GIN_ * GOUT_ + (size_t)n0 * GIN_;

    f32x4 acc[4][4] = {};

    const int qd0 = wave * 2;
    const int bn_sub = lane >> 2;  // 0..15 rows within a 16-row chunk
    const int bk_sub = lane & 3;   // which 8-element k-chunk

    for (int kk = 0; kk < 8; ++kk) {
        const int k0 = kk * 32;

        // ---- B stage: async global->LDS, 16 B/lane, 2 instrs per wave ----
#pragma unroll
        for (int s = 0; s < 2; ++s) {
            const int qd = qd0 + s;                       // 0..7 (wave-uniform)
            const int nloc = qd * 16 + bn_sub;            // 0..127
            const __hip_bfloat16* src = Wtg + nloc * GIN_ + k0 + bk_sub * 8;
            __builtin_amdgcn_global_load_lds(
                (const __attribute__((address_space(1))) unsigned int*)src,
                (__attribute__((address_space(3))) unsigned int*)(Bs + qd * 512),
                16, 0, 0);
        }

        // ---- A stage: f32 load -> bf16 convert -> LDS (fused cast) ----
#pragma unroll
        for (int itc = 0; itc < 4; ++itc) {
            const int c    = itc * 256 + t;   // 0..1023 float4-chunks
            const int row  = c >> 3;          // 0..127
            const int col4 = c & 7;           // 8 float4 per 32-float row
            const f32x4 v = *(const f32x4*)(xg + (size_t)row * LDX_ + k0 + col4 * 4);
            union { __hip_bfloat16 h[4]; unsigned long long u; } cv;
            cv.h[0] = __float2bfloat16(v.x);
            cv.h[1] = __float2bfloat16(v.y);
            cv.h[2] = __float2bfloat16(v.z);
            cv.h[3] = __float2bfloat16(v.w);
            *(unsigned long long*)(As + row * 32 + col4 * 4) = cv.u;
        }

        __syncthreads();

        // ---- fragments + MFMA ----
        bf16x8 af[4], bf[4];
#pragma unroll
        for (int mt = 0; mt < 4; ++mt)
            af[mt] = *(const bf16x8*)(As + (wrow * 64 + mt * 16 + lm) * 32 + quad * 8);
#pragma unroll
        for (int nt = 0; nt < 4; ++nt)
            bf[nt] = *(const bf16x8*)(Bs + (wcol * 64 + nt * 16 + lm) * 32 + quad * 8);
#pragma unroll
        for (int mt = 0; mt < 4; ++mt)
#pragma unroll
            for (int nt = 0; nt < 4; ++nt)
                acc[mt][nt] = __builtin_amdgcn_mfma_f32_16x16x32_bf16(
                    af[mt], bf[nt], acc[mt][nt], 0, 0, 0);

        __syncthreads();
    }

    // ---- epilogue: bias + rational, direct coalesced stores ----
    const float p0 = pc[g * 4 + 0], p1 = pc[g * 4 + 1];
    const float p2 = pc[g * 4 + 2], p3 = pc[g * 4 + 3];
    const float q0 = qc[g * 3 + 0], q1 = qc[g * 3 + 1], q2 = qc[g * 3 + 2];

#pragma unroll
    for (int nt = 0; nt < 4; ++nt) {
        const int col = n0 + wcol * 64 + nt * 16 + lm;      // 0..255 in group
        const float bb = bias[g * GOUT_ + col];
#pragma unroll
        for (int mt = 0; mt < 4; ++mt) {
#pragma unroll
            for (int r = 0; r < 4; ++r) {
                const int row = m0 + wrow * 64 + mt * 16 + quad * 4 + r;
                const float y  = acc[mt][nt][r] + bb;
                const float num = p0 + y * (p1 + y * (p2 + y * p3));
                const float den = 1.0f + fabsf(y * (q0 + y * (q1 + y * q2)));
                out[(size_t)row * LDX_ + g * GOUT_ + col] = num * __builtin_amdgcn_rcpf(den);
            }
        }
    }
}

extern "C" void kernel_launch(void* const* d_in, const int* in_sizes, int n_in,
                              void* d_out, int out_size, void* d_ws, size_t ws_size,
                              hipStream_t stream) {
    const float* x = (const float*)d_in[0];
    const float* W = (const float*)d_in[1];
    const float* b = (const float*)d_in[2];
    const float* p = (const float*)d_in[3];
    const float* q = (const float*)d_in[4];
    float* out = (float*)d_out;

    // d_ws: bf16 transposed weights, 8*256*256*2 = 1 MiB
    __hip_bfloat16* Wt = (__hip_bfloat16*)d_ws;

    wprep_kernel<<<128, 256, 0, stream>>>(W, Wt);
    gkan_kernel<<<1024, 256, 0, stream>>>(x, Wt, b, p, q, out);
}